// Round 10
// baseline (158.496 us; speedup 1.0000x reference)
//
#include <hip/hip_runtime.h>
#include <stdint.h>

#define N_TOK 8192
#define C_DIM 768
#define E_NUM 8
#define NT32 24               // K-tiles of 32
#define TOTX3 104             // 32 shared + up to 72 expert x-blocks (256-row units)
#define GRID3 312             // TOTX3 * 3 column-tiles; = 8 XCDs * 39
#define XXP3 13               // xx-values per XCD (104/8)

typedef short short8 __attribute__((ext_vector_type(8)));
typedef __bf16 bf16x8 __attribute__((ext_vector_type(8)));
typedef float f32x4 __attribute__((ext_vector_type(4)));

static __device__ __forceinline__ unsigned short f2bf(float f) {
    unsigned u = __float_as_uint(f);
    unsigned r = u + 0x7FFFu + ((u >> 16) & 1u);
    return (unsigned short)(r >> 16);
}
static __device__ __forceinline__ float bf2f(unsigned short h) {
    return __uint_as_float(((unsigned)h) << 16);
}

// ------------- transpose+convert weights: Wt[m][o][i] = W[m][i][o], bf16 -------------
__global__ void wtrans_kernel(const float* __restrict__ wfc, const float* __restrict__ wpj,
                              const float* __restrict__ w1, const float* __restrict__ w2,
                              unsigned short* __restrict__ Wt) {
    __shared__ float tile[32][33];
    const int m = blockIdx.z;
    const float* src = (m == 0) ? wfc : (m == 1) ? wpj
                     : (m < 10) ? (w1 + (size_t)(m - 2) * C_DIM * C_DIM)
                                : (w2 + (size_t)(m - 10) * C_DIM * C_DIM);
    const int i0 = blockIdx.y * 32;
    const int o0 = blockIdx.x * 32;
    #pragma unroll
    for (int rr = 0; rr < 32; rr += 8)
        tile[threadIdx.y + rr][threadIdx.x] = src[(size_t)(i0 + threadIdx.y + rr) * C_DIM + o0 + threadIdx.x];
    __syncthreads();
    unsigned short* dst = Wt + (size_t)m * C_DIM * C_DIM;
    #pragma unroll
    for (int rr = 0; rr < 32; rr += 8) {
        int o = o0 + threadIdx.y + rr;
        dst[(size_t)o * C_DIM + i0 + threadIdx.x] = f2bf(tile[threadIdx.x][threadIdx.y + rr]);
    }
}

// ---- router pass 1: fp32 logits, sigmoid, top-2 (no atomics); also emits xb = bf16(x) ----
__global__ void router_kernel(const float* __restrict__ x, const float* __restrict__ rw,
                              const float* __restrict__ bias,
                              float* __restrict__ topk_w, int* __restrict__ eids,
                              unsigned short* __restrict__ xb) {
    const int wave = threadIdx.x >> 6;
    const int lane = threadIdx.x & 63;
    const int n = blockIdx.x * 4 + wave;
    const float* xp = x + (size_t)n * C_DIM + lane * 12;
    float xv[12];
    #pragma unroll
    for (int j = 0; j < 12; j++) xv[j] = xp[j];
    unsigned short* xbp = xb + (size_t)n * C_DIM + lane * 12;
    #pragma unroll
    for (int j = 0; j < 12; j++) xbp[j] = f2bf(xv[j]);
    float acc[E_NUM];
    #pragma unroll
    for (int e = 0; e < E_NUM; e++) acc[e] = 0.f;
    #pragma unroll
    for (int e = 0; e < E_NUM; e++) {
        const float* wp = rw + (size_t)e * C_DIM + lane * 12;
        #pragma unroll
        for (int j = 0; j < 12; j++) acc[e] += xv[j] * wp[j];
    }
    #pragma unroll
    for (int e = 0; e < E_NUM; e++) {
        #pragma unroll
        for (int off = 32; off > 0; off >>= 1) acc[e] += __shfl_xor(acc[e], off, 64);
    }
    if (lane == 0) {
        float sc[E_NUM];
        #pragma unroll
        for (int e = 0; e < E_NUM; e++) sc[e] = 1.f / (1.f + expf(-acc[e]));
        int e0 = 0; float best = -1e30f;
        #pragma unroll
        for (int e = 0; e < E_NUM; e++) { float v = sc[e] + bias[e]; if (v > best) { best = v; e0 = e; } }
        int e1 = -1; float best1 = -1e30f;
        #pragma unroll
        for (int e = 0; e < E_NUM; e++) { if (e == e0) continue; float v = sc[e] + bias[e]; if (v > best1) { best1 = v; e1 = e; } }
        float w0 = sc[e0], w1 = sc[e1];
        float s = w0 + w1 + 1e-20f;
        w0 /= s; w1 /= s;
        topk_w[n * 2] = w0; topk_w[n * 2 + 1] = w1;
        eids[n * 2] = e0; eids[n * 2 + 1] = e1;
    }
}

// ---------------- router pass 2: per-expert compaction (deterministic) ----------------
__global__ __launch_bounds__(1024) void bucketize_kernel(const int* __restrict__ eids,
                                                         int* __restrict__ counts,
                                                         int* __restrict__ buckets) {
    const int e = blockIdx.x;
    const int t = threadIdx.x;
    const int wv = t >> 6, lane = t & 63;
    __shared__ int wave_tot[16];
    int running = 0;
    for (int start = 0; start < 2 * N_TOK; start += 1024) {
        const int i = start + t;
        const int f = (eids[i] == e) ? 1 : 0;
        unsigned long long mask = __ballot(f);
        int pre = __popcll(mask & ((1ull << lane) - 1ull));
        if (lane == 0) wave_tot[wv] = __popcll(mask);
        __syncthreads();
        int wbase = 0, tot = 0;
        #pragma unroll
        for (int j = 0; j < 16; j++) { int c = wave_tot[j]; tot += c; if (j < wv) wbase += c; }
        if (f) buckets[e * N_TOK + running + wbase + pre] = i;
        running += tot;
        __syncthreads();
    }
    if (t == 0) counts[e] = running;
}

// ---- block-offset prefix table (256-row units): xoffs[z] = first x-block of expert z ----
__global__ void prefix_kernel(const int* __restrict__ counts, int* __restrict__ xoffs) {
    if (threadIdx.x == 0 && blockIdx.x == 0) {
        int a = 0;
        for (int z = 0; z < E_NUM; z++) { xoffs[z] = a; a += (counts[z] + 255) >> 8; }
        xoffs[E_NUM] = a;            // shared starts here
        xoffs[E_NUM + 1] = a + 32;   // end of work (shared = 8192/256 = 32 blocks)
    }
}

// ---- merged bf16 MFMA GEMM: 256x256 tile, 8 waves, BK=32, depth-4 ring, counted vmcnt ----
// PHASE 0 (fc):   A = xb (shared direct; expert gather token=ent>>1); epi relu^2 -> Hsh[n] / H[ent]
// PHASE 1 (proj): A = Hsh (shared) / H gathered by ent (expert);      epi -> out[n] fp32 / Y[ent]
// 256^2 keeps r9's staging-bytes/FLOP win; depth-4 ring restores latency hiding WITHIN the block
// (r9's 1-block/CU lost the inter-block overlap r8 relied on). LDS: 4 bufs x 32 KiB
// (A 256x32 @0, B 256x32 @8192 ushorts) = 128 KiB. Per iter: WAITVM(8) [tiles kt+1,kt+2 stay in
// flight; drains only in 2-iter tail]; BAR; stage(kt+3) [safe: all waves passed BAR -> done
// reading buf[(kt+3)&3]'s old tile kt-1]; 12 ds_read_b128 + 32 MFMA.
// Bank swizzle (HW-verified r3/r6): 16B slot' = slot ^ ((row>>1)&3); pre-swizzled global source +
// linear gload_lds dest + swizzled ds_read.
#define GLOAD_LDS(g, l) __builtin_amdgcn_global_load_lds((const __attribute__((address_space(1))) void*)(g), (__attribute__((address_space(3))) void*)(l), 16, 0, 0)
#define WAITVM(n) asm volatile("s_waitcnt vmcnt(" #n ")" ::: "memory")
#define SCHEDB() __builtin_amdgcn_sched_barrier(0)
#define BAR() __builtin_amdgcn_s_barrier()

template <int PHASE>
__global__ __launch_bounds__(512, 2) void gemm_all_kernel(const unsigned short* __restrict__ Adir,
                                                          const unsigned short* __restrict__ Agat,
                                                          const unsigned short* __restrict__ WtAll,
                                                          void* __restrict__ dstDir,
                                                          unsigned short* __restrict__ dstGat,
                                                          const int* __restrict__ counts,
                                                          const int* __restrict__ buckets,
                                                          const int* __restrict__ xoffs) {
    // L2-locality decode: xcd-contiguous xx, y innermost
    const int fid = blockIdx.x;
    const int xcd = fid & 7;
    const int i3 = fid >> 3;              // 0..38
    const int xx = xcd * XXP3 + i3 / 3;
    const int y = i3 % 3;
    int xo[10];
    #pragma unroll
    for (int i = 0; i < 10; i++) xo[i] = xoffs[i];
    if (xx >= xo[9]) return;
    int z = E_NUM, xl = xx - xo[8];
    #pragma unroll
    for (int zz = 0; zz < E_NUM; zz++)
        if (xx >= xo[zz] && xx < xo[zz + 1]) { z = zz; xl = xx - xo[zz]; }
    const bool sh = (z == E_NUM);
    const int rows = sh ? N_TOK : counts[z];
    const int r0 = xl * 256;
    const int c0 = y * 256;

    __shared__ __align__(16) unsigned short lds[4 * 16384];   // 128 KiB, 4-buffer ring

    const int t = threadIdx.x;
    const int lane = t & 63;
    const int wv = t >> 6;
    const int wm = wv >> 2;               // 0..1 -> 128-row half
    const int wn = wv & 3;                // 0..3 -> 64-col quarter

    const int widx = sh ? (PHASE == 0 ? 0 : 1) : (PHASE == 0 ? 2 + z : 10 + z);
    const unsigned short* Bmat = WtAll + (size_t)widx * C_DIM * C_DIM;
    const int* bk = buckets + z * N_TOK;

    // staging: thread t covers rows {t>>2, 128+(t>>2)} of A and B, 16B slot t&3 (linear dest t*8),
    // global slot pre-swizzled: (t&3) ^ ((row>>1)&3), (row>>1)&3 == (t>>3)&3 (row+128 keeps &3)
    const int srow = t >> 2;                                     // 0..127
    const int scol = (((t & 3) ^ ((t >> 3) & 3)) * 8);           // pre-swizzled source col (elems)
    int grow0, grow1;
    const unsigned short* Asrc;
    if (sh) {
        Asrc = Adir;
        grow0 = r0 + srow; grow1 = r0 + 128 + srow;
    } else {
        Asrc = Agat;
        int p0 = r0 + srow, p1 = r0 + 128 + srow;
        int e0v = bk[p0 < rows ? p0 : 0];
        int e1v = bk[p1 < rows ? p1 : 0];
        grow0 = (PHASE == 0) ? (e0v >> 1) : e0v;
        grow1 = (PHASE == 0) ? (e1v >> 1) : e1v;
    }
    const unsigned short* ap0 = Asrc + (size_t)grow0 * C_DIM + scol;
    const unsigned short* ap1 = Asrc + (size_t)grow1 * C_DIM + scol;
    const unsigned short* bp0 = Bmat + (size_t)(c0 + srow) * C_DIM + scol;
    const unsigned short* bp1 = Bmat + (size_t)(c0 + 128 + srow) * C_DIM + scol;

    f32x4 acc[8][4];
    #pragma unroll
    for (int i = 0; i < 8; i++)
        #pragma unroll
        for (int j = 0; j < 4; j++) acc[i][j] = (f32x4){0.f, 0.f, 0.f, 0.f};

    // fragment-read swizzled k-slot: slot = fq, row&7 bits -> (fr>>1)&3
    const int fr = lane & 15;
    const int fq = lane >> 4;
    const int ks = ((fq ^ ((fr >> 1) & 3)) * 8);

    // prologue: stage tiles 0,1,2 into buffers 0,1,2 (12 vm-ops outstanding per thread)
    #pragma unroll
    for (int p = 0; p < 3; ++p) {
        unsigned short* d = lds + p * 16384 + t * 8;
        const int ko = p * 32;
        GLOAD_LDS(ap0 + ko, d);
        GLOAD_LDS(ap1 + ko, d + 4096);
        GLOAD_LDS(bp0 + ko, d + 8192);
        GLOAD_LDS(bp1 + ko, d + 12288);
    }

    #pragma unroll
    for (int kt = 0; kt < NT32; ++kt) {
        if (kt + 2 < NT32)      { WAITVM(8); }   // tile kt landed; kt+1,kt+2 stay in flight
        else if (kt + 1 < NT32) { WAITVM(4); }
        else                    { WAITVM(0); }
        BAR();          // tile kt visible; all waves done reading buf[(kt+3)&3]'s old tile
        SCHEDB();
        if (kt + 3 < NT32) {
            unsigned short* d = lds + ((kt + 3) & 3) * 16384 + t * 8;
            const int ko = (kt + 3) * 32;
            GLOAD_LDS(ap0 + ko, d);
            GLOAD_LDS(ap1 + ko, d + 4096);
            GLOAD_LDS(bp0 + ko, d + 8192);
            GLOAD_LDS(bp1 + ko, d + 12288);
        }
        SCHEDB();       // stage issued before compute; compute may not hoist above
        const unsigned short* buf = lds + (kt & 3) * 16384;
        short8 bfr[4];
        #pragma unroll
        for (int j = 0; j < 4; j++)
            bfr[j] = *reinterpret_cast<const short8*>(buf + 8192 + (size_t)(wn * 64 + j * 16 + fr) * 32 + ks);
        __builtin_amdgcn_s_setprio(1);
        #pragma unroll
        for (int i = 0; i < 8; i++) {
            short8 a = *reinterpret_cast<const short8*>(buf + (size_t)(wm * 128 + i * 16 + fr) * 32 + ks);
            #pragma unroll
            for (int j = 0; j < 4; j++)
                acc[i][j] = __builtin_amdgcn_mfma_f32_16x16x32_bf16(
                    __builtin_bit_cast(bf16x8, a), __builtin_bit_cast(bf16x8, bfr[j]), acc[i][j], 0, 0, 0);
        }
        __builtin_amdgcn_s_setprio(0);
        // single barrier per step: next iter's stage targets the buffer whose readers all
        // passed this step's BAR before it gets overwritten.
    }

    // ---- epilogue: rows r0 + wm*128 + i*16 + fq*4 + rr; cols c0 + wn*64 + j*16 + fr ----
    const int orow = r0 + wm * 128;
    const int ocol = c0 + wn * 64;
    if (sh) {
        if constexpr (PHASE == 0) {
            unsigned short* Hd = (unsigned short*)dstDir;
            #pragma unroll
            for (int i = 0; i < 8; i++)
                #pragma unroll
                for (int rr = 0; rr < 4; rr++) {
                    size_t base = (size_t)(orow + i * 16 + fq * 4 + rr) * C_DIM;
                    #pragma unroll
                    for (int j = 0; j < 4; j++) {
                        float v = acc[i][j][rr];
                        float rl = v > 0.f ? v : 0.f;
                        Hd[base + ocol + j * 16 + fr] = f2bf(rl * rl);
                    }
                }
        } else {
            float* od = (float*)dstDir;
            #pragma unroll
            for (int i = 0; i < 8; i++)
                #pragma unroll
                for (int rr = 0; rr < 4; rr++) {
                    size_t base = (size_t)(orow + i * 16 + fq * 4 + rr) * C_DIM;
                    #pragma unroll
                    for (int j = 0; j < 4; j++)
                        od[base + ocol + j * 16 + fr] = acc[i][j][rr];
                }
        }
    } else {
        #pragma unroll
        for (int i = 0; i < 8; i++)
            #pragma unroll
            for (int rr = 0; rr < 4; rr++) {
                int pos = orow + i * 16 + fq * 4 + rr;
                if (pos < rows) {
                    int ent = bk[pos];
                    size_t base = (size_t)ent * C_DIM;
                    #pragma unroll
                    for (int j = 0; j < 4; j++) {
                        float v = acc[i][j][rr];
                        if (PHASE == 0) {
                            float rl = v > 0.f ? v : 0.f;
                            dstGat[base + ocol + j * 16 + fr] = f2bf(rl * rl);
                        } else {
                            dstGat[base + ocol + j * 16 + fr] = f2bf(v);
                        }
                    }
                }
            }
    }
}

// ---------------- combine: out += w0*Y[n,0] + w1*Y[n,1] ----------------
__global__ void combine_kernel(float* __restrict__ out, const unsigned short* __restrict__ Y,
                               const float* __restrict__ tw) {
    int idx = blockIdx.x * blockDim.x + threadIdx.x;
    const int per_row = C_DIM / 4;
    if (idx >= N_TOK * per_row) return;
    int n = idx / per_row;
    int c = (idx % per_row) * 4;
    float w0 = tw[n * 2], w1 = tw[n * 2 + 1];
    const ushort4 a = *reinterpret_cast<const ushort4*>(Y + (size_t)(n * 2) * C_DIM + c);
    const ushort4 b = *reinterpret_cast<const ushort4*>(Y + (size_t)(n * 2 + 1) * C_DIM + c);
    float4* op = reinterpret_cast<float4*>(out + (size_t)n * C_DIM + c);
    float4 o = *op;
    o.x += w0 * bf2f(a.x) + w1 * bf2f(b.x);
    o.y += w0 * bf2f(a.y) + w1 * bf2f(b.y);
    o.z += w0 * bf2f(a.z) + w1 * bf2f(b.z);
    o.w += w0 * bf2f(a.w) + w1 * bf2f(b.w);
    *op = o;
}

extern "C" void kernel_launch(void* const* d_in, const int* in_sizes, int n_in,
                              void* d_out, int out_size, void* d_ws, size_t ws_size,
                              hipStream_t stream) {
    const float* x   = (const float*)d_in[0];
    const float* wfc = (const float*)d_in[1];
    const float* wpj = (const float*)d_in[2];
    const float* w1  = (const float*)d_in[3];
    const float* w2  = (const float*)d_in[4];
    const float* rw  = (const float*)d_in[5];
    const float* bias= (const float*)d_in[6];
    float* out = (float*)d_out;

    char* ws = (char*)d_ws;
    size_t off = 0;
    auto alloc = [&](size_t bytes) { void* p = ws + off; off += (bytes + 255) & ~(size_t)255; return p; };
    unsigned short* xb   = (unsigned short*)alloc((size_t)N_TOK * C_DIM * 2);
    unsigned short* Wt   = (unsigned short*)alloc((size_t)18 * C_DIM * C_DIM * 2);
    unsigned short* H    = (unsigned short*)alloc((size_t)N_TOK * 2 * C_DIM * 2);  // expert hidden, by entry
    unsigned short* Hsh  = (unsigned short*)alloc((size_t)N_TOK * C_DIM * 2);      // shared hidden
    unsigned short* Y    = (unsigned short*)alloc((size_t)N_TOK * 2 * C_DIM * 2);  // expert out, by entry
    float* topk_w        = (float*)alloc((size_t)N_TOK * 2 * 4);
    int* counts          = (int*)alloc(256);
    int* buckets         = (int*)alloc((size_t)E_NUM * N_TOK * 4);
    int* eids            = (int*)alloc((size_t)2 * N_TOK * 4);
    int* xoffs           = (int*)alloc(64);

    wtrans_kernel<<<dim3(24, 24, 18), dim3(32, 8), 0, stream>>>(wfc, wpj, w1, w2, Wt);
    router_kernel<<<N_TOK / 4, 256, 0, stream>>>(x, rw, bias, topk_w, eids, xb);
    bucketize_kernel<<<E_NUM, 1024, 0, stream>>>(eids, counts, buckets);
    prefix_kernel<<<1, 64, 0, stream>>>(counts, xoffs);

    gemm_all_kernel<0><<<GRID3, 512, 0, stream>>>(xb, xb, Wt, Hsh, H, counts, buckets, xoffs);
    gemm_all_kernel<1><<<GRID3, 512, 0, stream>>>(Hsh, H, Wt, out, Y, counts, buckets, xoffs);

    combine_kernel<<<(N_TOK * (C_DIM / 4) + 255) / 256, 256, 0, stream>>>(out, Y, topk_w);
}

// Round 11
// 145.239 us; speedup vs baseline: 1.0913x; 1.0913x over previous
//
#include <hip/hip_runtime.h>
#include <stdint.h>

#define N_TOK 8192
#define C_DIM 768
#define E_NUM 8
#define NTK 24                // K-tiles of 32
#define GRIDG 624             // 8 xcd * 78 ; 78 = 13 q * 6 y
#define PREP_WT 10368         // 18 mats * 24 * 24 tiles
#define PREP_TOT (PREP_WT + N_TOK / 4)

typedef short short8 __attribute__((ext_vector_type(8)));
typedef __bf16 bf16x8 __attribute__((ext_vector_type(8)));
typedef float f32x4 __attribute__((ext_vector_type(4)));

static __device__ __forceinline__ unsigned short f2bf(float f) {
    unsigned u = __float_as_uint(f);
    unsigned r = u + 0x7FFFu + ((u >> 16) & 1u);
    return (unsigned short)(r >> 16);
}
static __device__ __forceinline__ float bf2f(unsigned short h) {
    return __uint_as_float(((unsigned)h) << 16);
}

// ---- fused prep: blocks [0,10368) transpose+convert weights; [10368,..) router top-2 + xb ----
__global__ __launch_bounds__(256) void prep_kernel(const float* __restrict__ wfc,
                                                   const float* __restrict__ wpj,
                                                   const float* __restrict__ w1,
                                                   const float* __restrict__ w2,
                                                   unsigned short* __restrict__ Wt,
                                                   const float* __restrict__ x,
                                                   const float* __restrict__ rw,
                                                   const float* __restrict__ bias,
                                                   float* __restrict__ topk_w,
                                                   int* __restrict__ eids,
                                                   unsigned short* __restrict__ xb) {
    __shared__ float tile[32][33];
    const int bx = blockIdx.x;
    const int t = threadIdx.x;
    if (bx < PREP_WT) {
        const int m = bx / 576;
        const int rem = bx - m * 576;
        const int i0 = (rem / 24) * 32;
        const int o0 = (rem % 24) * 32;
        const int tx = t & 31, ty = t >> 5;   // 32 x 8
        const float* src = (m == 0) ? wfc : (m == 1) ? wpj
                         : (m < 10) ? (w1 + (size_t)(m - 2) * C_DIM * C_DIM)
                                    : (w2 + (size_t)(m - 10) * C_DIM * C_DIM);
        #pragma unroll
        for (int rr = 0; rr < 32; rr += 8)
            tile[ty + rr][tx] = src[(size_t)(i0 + ty + rr) * C_DIM + o0 + tx];
        __syncthreads();
        unsigned short* dst = Wt + (size_t)m * C_DIM * C_DIM;
        #pragma unroll
        for (int rr = 0; rr < 32; rr += 8) {
            int o = o0 + ty + rr;
            dst[(size_t)o * C_DIM + i0 + tx] = f2bf(tile[tx][ty + rr]);
        }
    } else {
        const int rb = bx - PREP_WT;
        const int wave = t >> 6;
        const int lane = t & 63;
        const int n = rb * 4 + wave;
        const float* xp = x + (size_t)n * C_DIM + lane * 12;
        float xv[12];
        #pragma unroll
        for (int j = 0; j < 12; j++) xv[j] = xp[j];
        unsigned short* xbp = xb + (size_t)n * C_DIM + lane * 12;
        #pragma unroll
        for (int j = 0; j < 12; j++) xbp[j] = f2bf(xv[j]);
        float acc[E_NUM];
        #pragma unroll
        for (int e = 0; e < E_NUM; e++) acc[e] = 0.f;
        #pragma unroll
        for (int e = 0; e < E_NUM; e++) {
            const float* wp = rw + (size_t)e * C_DIM + lane * 12;
            #pragma unroll
            for (int j = 0; j < 12; j++) acc[e] += xv[j] * wp[j];
        }
        #pragma unroll
        for (int e = 0; e < E_NUM; e++) {
            #pragma unroll
            for (int off = 32; off > 0; off >>= 1) acc[e] += __shfl_xor(acc[e], off, 64);
        }
        if (lane == 0) {
            float sc[E_NUM];
            #pragma unroll
            for (int e = 0; e < E_NUM; e++) sc[e] = 1.f / (1.f + expf(-acc[e]));
            int e0 = 0; float best = -1e30f;
            #pragma unroll
            for (int e = 0; e < E_NUM; e++) { float v = sc[e] + bias[e]; if (v > best) { best = v; e0 = e; } }
            int e1 = -1; float best1 = -1e30f;
            #pragma unroll
            for (int e = 0; e < E_NUM; e++) { if (e == e0) continue; float v = sc[e] + bias[e]; if (v > best1) { best1 = v; e1 = e; } }
            float w0 = sc[e0], w1 = sc[e1];
            float s = w0 + w1 + 1e-20f;
            w0 /= s; w1 /= s;
            topk_w[n * 2] = w0; topk_w[n * 2 + 1] = w1;
            eids[n * 2] = e0; eids[n * 2 + 1] = e1;
        }
    }
}

// ---------------- router pass 2: per-expert compaction (deterministic) ----------------
__global__ __launch_bounds__(1024) void bucketize_kernel(const int* __restrict__ eids,
                                                         int* __restrict__ counts,
                                                         int* __restrict__ buckets) {
    const int e = blockIdx.x;
    const int t = threadIdx.x;
    const int wv = t >> 6, lane = t & 63;
    __shared__ int wave_tot[16];
    int running = 0;
    for (int start = 0; start < 2 * N_TOK; start += 1024) {
        const int i = start + t;
        const int f = (eids[i] == e) ? 1 : 0;
        unsigned long long mask = __ballot(f);
        int pre = __popcll(mask & ((1ull << lane) - 1ull));
        if (lane == 0) wave_tot[wv] = __popcll(mask);
        __syncthreads();
        int wbase = 0, tot = 0;
        #pragma unroll
        for (int j = 0; j < 16; j++) { int c = wave_tot[j]; tot += c; if (j < wv) wbase += c; }
        if (f) buckets[e * N_TOK + running + wbase + pre] = i;
        running += tot;
        __syncthreads();
    }
    if (t == 0) counts[e] = running;
}

// ---- merged bf16 MFMA GEMM: 256x128 tile, 8 waves (64x64 each), BK=32 dbuf, 2 blocks/CU ----
// PHASE 0 (fc):   A = xb (shared direct; expert gather token=ent>>1); epi relu^2 -> Hsh[n] / H[ent]
// PHASE 1 (proj): A = Hsh (shared) / H gathered by ent (expert);      epi -> out[n] fp32 / Y[ent]
// Ratio: (256+128)/(256*128) = 1.33x less staged bytes/FLOP than 128^2 (r8), while keeping the
// fine-grained grid + 2 blocks/CU residency that made r8 the best measured config.
// Grid: 624 = 8 xcd * 13 q * 6 y; xx = xcd + 8q (round-robin balance), y innermost (A L2 reuse).
// xoffs computed per-block from counts (prefix kernel deleted). LDS: 2 x 24 KiB
// (A 256x32 @0, B 128x32 @8192 ushorts). Schedule (r8-proven): WAITVM0; BAR; stage(kt+1) into
// other buffer; 8 ds_read_b128 + 16 MFMA. Bank swizzle (HW-verified r3): 16B slot' =
// slot ^ ((row>>1)&3); pre-swizzled global source + linear gload_lds dest + swizzled ds_read.
#define GLOAD_LDS(g, l) __builtin_amdgcn_global_load_lds((const __attribute__((address_space(1))) void*)(g), (__attribute__((address_space(3))) void*)(l), 16, 0, 0)
#define WAITVM0() asm volatile("s_waitcnt vmcnt(0)" ::: "memory")
#define SCHEDB() __builtin_amdgcn_sched_barrier(0)
#define BAR() __builtin_amdgcn_s_barrier()

template <int PHASE>
__global__ __launch_bounds__(512, 4) void gemm_all_kernel(const unsigned short* __restrict__ Adir,
                                                          const unsigned short* __restrict__ Agat,
                                                          const unsigned short* __restrict__ WtAll,
                                                          void* __restrict__ dstDir,
                                                          unsigned short* __restrict__ dstGat,
                                                          const int* __restrict__ counts,
                                                          const int* __restrict__ buckets) {
    const int fid = blockIdx.x;
    const int xcd = fid & 7;
    const int i6 = fid >> 3;              // 0..77
    const int xx = xcd + 8 * (i6 / 6);    // round-robin xx over XCDs
    const int y = i6 % 6;
    // per-block prefix from counts (256-row units)
    int cz[E_NUM];
    #pragma unroll
    for (int zz = 0; zz < E_NUM; zz++) cz[zz] = counts[zz];
    int xo[E_NUM + 1]; int a = 0;
    #pragma unroll
    for (int zz = 0; zz < E_NUM; zz++) { xo[zz] = a; a += (cz[zz] + 255) >> 8; }
    xo[E_NUM] = a;
    if (xx >= a + 32) return;
    const bool sh = (xx >= a);
    int z = 0, xl = xx - a;
    if (!sh) {
        #pragma unroll
        for (int zz = 0; zz < E_NUM; zz++)
            if (xx >= xo[zz] && xx < xo[zz + 1]) { z = zz; xl = xx - xo[zz]; }
    }
    const int rows = sh ? N_TOK : cz[z];
    const int r0 = xl * 256;
    const int c0 = y * 128;

    __shared__ __align__(16) unsigned short lds[2 * 12288];   // 48 KiB double buffer

    const int t = threadIdx.x;
    const int lane = t & 63;
    const int wv = t >> 6;
    const int wm = wv >> 1;               // 0..3 -> 64-row band
    const int wn = wv & 1;                // 0..1 -> 64-col band

    const int widx = sh ? (PHASE == 0 ? 0 : 1) : (PHASE == 0 ? 2 + z : 10 + z);
    const unsigned short* Bmat = WtAll + (size_t)widx * C_DIM * C_DIM;
    const int* bk = buckets + z * N_TOK;

    // staging geometry: slot index S -> row S>>2, 16B slot S&3 (==lane&3).
    // A instr j (j=0,1): S = (j*8+wv)*64 + lane -> rows j*128 + wv*16 + (lane>>2)
    // B instr:           S = wv*64 + lane       -> rows wv*16 + (lane>>2)
    // global source col pre-swizzled: (S&3) ^ ((row>>1)&3) == (lane&3) ^ ((lane>>3)&3)
    const int scol = (((lane & 3) ^ ((lane >> 3) & 3)) * 8);
    const int rA0 = wv * 16 + (lane >> 2);
    const int rA1 = 128 + rA0;
    int g0, g1;
    const unsigned short* Asrc;
    if (sh) {
        Asrc = Adir;
        g0 = r0 + rA0; g1 = r0 + rA1;
    } else {
        Asrc = Agat;
        int p0 = r0 + rA0, p1 = r0 + rA1;
        int e0v = bk[p0 < rows ? p0 : rows - 1];
        int e1v = bk[p1 < rows ? p1 : rows - 1];
        g0 = (PHASE == 0) ? (e0v >> 1) : e0v;
        g1 = (PHASE == 0) ? (e1v >> 1) : e1v;
    }
    const unsigned short* ap0 = Asrc + (size_t)g0 * C_DIM + scol;
    const unsigned short* ap1 = Asrc + (size_t)g1 * C_DIM + scol;
    const unsigned short* bp  = Bmat + (size_t)(c0 + rA0) * C_DIM + scol;

    f32x4 acc[4][4];
    #pragma unroll
    for (int i = 0; i < 4; i++)
        #pragma unroll
        for (int j = 0; j < 4; j++) acc[i][j] = (f32x4){0.f, 0.f, 0.f, 0.f};

    // fragment-read swizzled k-slot: slot = fq ^ ((fr>>1)&3)
    const int fr = lane & 15;
    const int fq = lane >> 4;
    const int ks = ((fq ^ ((fr >> 1) & 3)) * 8);

    // prologue: stage tile 0 into buffer 0 (3 vm-ops per thread)
    GLOAD_LDS(ap0, lds + wv * 512 + lane * 8);
    GLOAD_LDS(ap1, lds + 4096 + wv * 512 + lane * 8);
    GLOAD_LDS(bp,  lds + 8192 + wv * 512 + lane * 8);

    #pragma unroll
    for (int kt = 0; kt < NTK; ++kt) {
        WAITVM0();      // tile kt's loads (issued one full compute-phase ago) complete
        BAR();          // tile kt visible; prior readers of the other buffer are done
        SCHEDB();
        if (kt + 1 < NTK) {
            unsigned short* d = lds + ((kt + 1) & 1) * 12288;
            const int ko = (kt + 1) * 32;
            GLOAD_LDS(ap0 + ko, d + wv * 512 + lane * 8);
            GLOAD_LDS(ap1 + ko, d + 4096 + wv * 512 + lane * 8);
            GLOAD_LDS(bp + ko,  d + 8192 + wv * 512 + lane * 8);
        }
        SCHEDB();       // stage issued before compute; compute may not hoist above
        const unsigned short* buf = lds + (kt & 1) * 12288;
        short8 afr[4], bfr[4];
        #pragma unroll
        for (int i = 0; i < 4; i++)
            afr[i] = *reinterpret_cast<const short8*>(buf + (size_t)(wm * 64 + i * 16 + fr) * 32 + ks);
        #pragma unroll
        for (int j = 0; j < 4; j++)
            bfr[j] = *reinterpret_cast<const short8*>(buf + 8192 + (size_t)(wn * 64 + j * 16 + fr) * 32 + ks);
        __builtin_amdgcn_s_setprio(1);
        #pragma unroll
        for (int i = 0; i < 4; i++)
            #pragma unroll
            for (int j = 0; j < 4; j++)
                acc[i][j] = __builtin_amdgcn_mfma_f32_16x16x32_bf16(
                    __builtin_bit_cast(bf16x8, afr[i]), __builtin_bit_cast(bf16x8, bfr[j]), acc[i][j], 0, 0, 0);
        __builtin_amdgcn_s_setprio(0);
        // single barrier per step: next iter's stage targets the buffer whose readers all
        // passed this step's BAR before it gets overwritten (r8-proven).
    }

    // ---- epilogue: rows r0 + wm*64 + i*16 + fq*4 + rr; cols c0 + wn*64 + j*16 + fr ----
    const int orow = r0 + wm * 64;
    const int ocol = c0 + wn * 64;
    if (sh) {
        if constexpr (PHASE == 0) {
            unsigned short* Hd = (unsigned short*)dstDir;
            #pragma unroll
            for (int i = 0; i < 4; i++)
                #pragma unroll
                for (int rr = 0; rr < 4; rr++) {
                    size_t base = (size_t)(orow + i * 16 + fq * 4 + rr) * C_DIM;
                    #pragma unroll
                    for (int j = 0; j < 4; j++) {
                        float v = acc[i][j][rr];
                        float rl = v > 0.f ? v : 0.f;
                        Hd[base + ocol + j * 16 + fr] = f2bf(rl * rl);
                    }
                }
        } else {
            float* od = (float*)dstDir;
            #pragma unroll
            for (int i = 0; i < 4; i++)
                #pragma unroll
                for (int rr = 0; rr < 4; rr++) {
                    size_t base = (size_t)(orow + i * 16 + fq * 4 + rr) * C_DIM;
                    #pragma unroll
                    for (int j = 0; j < 4; j++)
                        od[base + ocol + j * 16 + fr] = acc[i][j][rr];
                }
        }
    } else {
        #pragma unroll
        for (int i = 0; i < 4; i++)
            #pragma unroll
            for (int rr = 0; rr < 4; rr++) {
                int pos = orow + i * 16 + fq * 4 + rr;
                if (pos < rows) {
                    int ent = bk[pos];
                    size_t base = (size_t)ent * C_DIM;
                    #pragma unroll
                    for (int j = 0; j < 4; j++) {
                        float v = acc[i][j][rr];
                        if (PHASE == 0) {
                            float rl = v > 0.f ? v : 0.f;
                            dstGat[base + ocol + j * 16 + fr] = f2bf(rl * rl);
                        } else {
                            dstGat[base + ocol + j * 16 + fr] = f2bf(v);
                        }
                    }
                }
            }
    }
}

// ---------------- combine: out += w0*Y[n,0] + w1*Y[n,1] ----------------
__global__ void combine_kernel(float* __restrict__ out, const unsigned short* __restrict__ Y,
                               const float* __restrict__ tw) {
    int idx = blockIdx.x * blockDim.x + threadIdx.x;
    const int per_row = C_DIM / 4;
    if (idx >= N_TOK * per_row) return;
    int n = idx / per_row;
    int c = (idx % per_row) * 4;
    float w0 = tw[n * 2], w1 = tw[n * 2 + 1];
    const ushort4 a = *reinterpret_cast<const ushort4*>(Y + (size_t)(n * 2) * C_DIM + c);
    const ushort4 b = *reinterpret_cast<const ushort4*>(Y + (size_t)(n * 2 + 1) * C_DIM + c);
    float4* op = reinterpret_cast<float4*>(out + (size_t)n * C_DIM + c);
    float4 o = *op;
    o.x += w0 * bf2f(a.x) + w1 * bf2f(b.x);
    o.y += w0 * bf2f(a.y) + w1 * bf2f(b.y);
    o.z += w0 * bf2f(a.z) + w1 * bf2f(b.z);
    o.w += w0 * bf2f(a.w) + w1 * bf2f(b.w);
    *op = o;
}

extern "C" void kernel_launch(void* const* d_in, const int* in_sizes, int n_in,
                              void* d_out, int out_size, void* d_ws, size_t ws_size,
                              hipStream_t stream) {
    const float* x   = (const float*)d_in[0];
    const float* wfc = (const float*)d_in[1];
    const float* wpj = (const float*)d_in[2];
    const float* w1  = (const float*)d_in[3];
    const float* w2  = (const float*)d_in[4];
    const float* rw  = (const float*)d_in[5];
    const float* bias= (const float*)d_in[6];
    float* out = (float*)d_out;

    char* ws = (char*)d_ws;
    size_t off = 0;
    auto alloc = [&](size_t bytes) { void* p = ws + off; off += (bytes + 255) & ~(size_t)255; return p; };
    unsigned short* xb   = (unsigned short*)alloc((size_t)N_TOK * C_DIM * 2);
    unsigned short* Wt   = (unsigned short*)alloc((size_t)18 * C_DIM * C_DIM * 2);
    unsigned short* H    = (unsigned short*)alloc((size_t)N_TOK * 2 * C_DIM * 2);  // expert hidden, by entry
    unsigned short* Hsh  = (unsigned short*)alloc((size_t)N_TOK * C_DIM * 2);      // shared hidden
    unsigned short* Y    = (unsigned short*)alloc((size_t)N_TOK * 2 * C_DIM * 2);  // expert out, by entry
    float* topk_w        = (float*)alloc((size_t)N_TOK * 2 * 4);
    int* counts          = (int*)alloc(256);
    int* buckets         = (int*)alloc((size_t)E_NUM * N_TOK * 4);
    int* eids            = (int*)alloc((size_t)2 * N_TOK * 4);

    prep_kernel<<<PREP_TOT, 256, 0, stream>>>(wfc, wpj, w1, w2, Wt, x, rw, bias, topk_w, eids, xb);
    bucketize_kernel<<<E_NUM, 1024, 0, stream>>>(eids, counts, buckets);

    gemm_all_kernel<0><<<GRIDG, 512, 0, stream>>>(xb, xb, Wt, Hsh, H, counts, buckets);
    gemm_all_kernel<1><<<GRIDG, 512, 0, stream>>>(Hsh, H, Wt, out, Y, counts, buckets);

    combine_kernel<<<(N_TOK * (C_DIM / 4) + 255) / 256, 256, 0, stream>>>(out, Y, topk_w);
}

// Round 12
// 131.522 us; speedup vs baseline: 1.2051x; 1.1043x over previous
//
#include <hip/hip_runtime.h>
#include <stdint.h>

#define N_TOK 8192
#define C_DIM 768
#define E_NUM 8
#define NTK 24                // K-tiles of 32
#define GRIDG 624             // 8 xcd * 13 q * 6 y
#define PREP_WT 10368         // 18 mats * 24 * 24 tiles
#define PREP_TOT (PREP_WT + N_TOK / 4)

typedef short short8 __attribute__((ext_vector_type(8)));
typedef __bf16 bf16x8 __attribute__((ext_vector_type(8)));
typedef float f32x4 __attribute__((ext_vector_type(4)));

static __device__ __forceinline__ unsigned short f2bf(float f) {
    unsigned u = __float_as_uint(f);
    unsigned r = u + 0x7FFFu + ((u >> 16) & 1u);
    return (unsigned short)(r >> 16);
}
static __device__ __forceinline__ float bf2f(unsigned short h) {
    return __uint_as_float(((unsigned)h) << 16);
}

// ---- fused prep: blocks [0,10368) transpose+convert weights; [10368,..) router top-2 + xb ----
__global__ __launch_bounds__(256) void prep_kernel(const float* __restrict__ wfc,
                                                   const float* __restrict__ wpj,
                                                   const float* __restrict__ w1,
                                                   const float* __restrict__ w2,
                                                   unsigned short* __restrict__ Wt,
                                                   const float* __restrict__ x,
                                                   const float* __restrict__ rw,
                                                   const float* __restrict__ bias,
                                                   float* __restrict__ topk_w,
                                                   int* __restrict__ eids,
                                                   unsigned short* __restrict__ xb) {
    __shared__ float tile[32][33];
    const int bx = blockIdx.x;
    const int t = threadIdx.x;
    if (bx < PREP_WT) {
        const int m = bx / 576;
        const int rem = bx - m * 576;
        const int i0 = (rem / 24) * 32;
        const int o0 = (rem % 24) * 32;
        const int tx = t & 31, ty = t >> 5;   // 32 x 8
        const float* src = (m == 0) ? wfc : (m == 1) ? wpj
                         : (m < 10) ? (w1 + (size_t)(m - 2) * C_DIM * C_DIM)
                                    : (w2 + (size_t)(m - 10) * C_DIM * C_DIM);
        #pragma unroll
        for (int rr = 0; rr < 32; rr += 8)
            tile[ty + rr][tx] = src[(size_t)(i0 + ty + rr) * C_DIM + o0 + tx];
        __syncthreads();
        unsigned short* dst = Wt + (size_t)m * C_DIM * C_DIM;
        #pragma unroll
        for (int rr = 0; rr < 32; rr += 8) {
            int o = o0 + ty + rr;
            dst[(size_t)o * C_DIM + i0 + tx] = f2bf(tile[tx][ty + rr]);
        }
    } else {
        const int rb = bx - PREP_WT;
        const int wave = t >> 6;
        const int lane = t & 63;
        const int n = rb * 4 + wave;
        const float* xp = x + (size_t)n * C_DIM + lane * 12;
        float xv[12];
        #pragma unroll
        for (int j = 0; j < 12; j++) xv[j] = xp[j];
        unsigned short* xbp = xb + (size_t)n * C_DIM + lane * 12;
        #pragma unroll
        for (int j = 0; j < 12; j++) xbp[j] = f2bf(xv[j]);
        float acc[E_NUM];
        #pragma unroll
        for (int e = 0; e < E_NUM; e++) acc[e] = 0.f;
        #pragma unroll
        for (int e = 0; e < E_NUM; e++) {
            const float* wp = rw + (size_t)e * C_DIM + lane * 12;
            #pragma unroll
            for (int j = 0; j < 12; j++) acc[e] += xv[j] * wp[j];
        }
        #pragma unroll
        for (int e = 0; e < E_NUM; e++) {
            #pragma unroll
            for (int off = 32; off > 0; off >>= 1) acc[e] += __shfl_xor(acc[e], off, 64);
        }
        if (lane == 0) {
            float sc[E_NUM];
            #pragma unroll
            for (int e = 0; e < E_NUM; e++) sc[e] = 1.f / (1.f + expf(-acc[e]));
            int e0 = 0; float best = -1e30f;
            #pragma unroll
            for (int e = 0; e < E_NUM; e++) { float v = sc[e] + bias[e]; if (v > best) { best = v; e0 = e; } }
            int e1 = -1; float best1 = -1e30f;
            #pragma unroll
            for (int e = 0; e < E_NUM; e++) { if (e == e0) continue; float v = sc[e] + bias[e]; if (v > best1) { best1 = v; e1 = e; } }
            float w0 = sc[e0], w1 = sc[e1];
            float s = w0 + w1 + 1e-20f;
            w0 /= s; w1 /= s;
            topk_w[n * 2] = w0; topk_w[n * 2 + 1] = w1;
            eids[n * 2] = e0; eids[n * 2 + 1] = e1;
        }
    }
}

// ---------------- router pass 2: per-expert compaction (deterministic) ----------------
__global__ __launch_bounds__(1024) void bucketize_kernel(const int* __restrict__ eids,
                                                         int* __restrict__ counts,
                                                         int* __restrict__ buckets) {
    const int e = blockIdx.x;
    const int t = threadIdx.x;
    const int wv = t >> 6, lane = t & 63;
    __shared__ int wave_tot[16];
    int running = 0;
    for (int start = 0; start < 2 * N_TOK; start += 1024) {
        const int i = start + t;
        const int f = (eids[i] == e) ? 1 : 0;
        unsigned long long mask = __ballot(f);
        int pre = __popcll(mask & ((1ull << lane) - 1ull));
        if (lane == 0) wave_tot[wv] = __popcll(mask);
        __syncthreads();
        int wbase = 0, tot = 0;
        #pragma unroll
        for (int j = 0; j < 16; j++) { int c = wave_tot[j]; tot += c; if (j < wv) wbase += c; }
        if (f) buckets[e * N_TOK + running + wbase + pre] = i;
        running += tot;
        __syncthreads();
    }
    if (t == 0) counts[e] = running;
}

// ---- merged bf16 MFMA GEMM: 256x128 tile, 8 waves, BK=32, 3-buffer ring, counted vmcnt ----
// PHASE 0 (fc):   A = xb (shared direct; expert gather token=ent>>1); epi relu^2 -> Hsh[n] / H[ent]
// PHASE 1 (proj): A = Hsh (shared) / H gathered by ent (expert);      epi -> out[n] fp32 / Y[ent]
// r11 post-mortem fixes: (1) XCD-contiguous xx (r7-proven: FETCH 65 -> ~35 MB, B-panels stay on
// 1-2 XCD L2s); (2) 3-buffer ring, 72 KiB (still 2 blocks/CU) with counted WAITVM(3) -- tiles
// kt+1,kt+2 stay in flight, no drain until the tail. Single barrier per step stays safe:
// stage(kt+2) overwrites buf[(kt-1)%3], whose readers all passed BAR(kt).
// Bank swizzle (HW-verified r3): 16B slot' = slot ^ ((row>>1)&3); pre-swizzled global source +
// linear gload_lds dest + swizzled ds_read.
#define GLOAD_LDS(g, l) __builtin_amdgcn_global_load_lds((const __attribute__((address_space(1))) void*)(g), (__attribute__((address_space(3))) void*)(l), 16, 0, 0)
#define WAITVM(n) asm volatile("s_waitcnt vmcnt(" #n ")" ::: "memory")
#define SCHEDB() __builtin_amdgcn_sched_barrier(0)
#define BAR() __builtin_amdgcn_s_barrier()

template <int PHASE>
__global__ __launch_bounds__(512, 4) void gemm_all_kernel(const unsigned short* __restrict__ Adir,
                                                          const unsigned short* __restrict__ Agat,
                                                          const unsigned short* __restrict__ WtAll,
                                                          void* __restrict__ dstDir,
                                                          unsigned short* __restrict__ dstGat,
                                                          const int* __restrict__ counts,
                                                          const int* __restrict__ buckets) {
    const int fid = blockIdx.x;
    const int xcd = fid & 7;
    const int i6 = fid >> 3;              // 0..77
    const int xx = xcd * 13 + i6 / 6;     // XCD-contiguous xx (L2 locality, r7-proven)
    const int y = i6 % 6;
    // per-block prefix from counts (256-row units)
    int cz[E_NUM];
    #pragma unroll
    for (int zz = 0; zz < E_NUM; zz++) cz[zz] = counts[zz];
    int xo[E_NUM + 1]; int a = 0;
    #pragma unroll
    for (int zz = 0; zz < E_NUM; zz++) { xo[zz] = a; a += (cz[zz] + 255) >> 8; }
    xo[E_NUM] = a;
    if (xx >= a + 32) return;
    const bool sh = (xx >= a);
    int z = 0, xl = xx - a;
    if (!sh) {
        #pragma unroll
        for (int zz = 0; zz < E_NUM; zz++)
            if (xx >= xo[zz] && xx < xo[zz + 1]) { z = zz; xl = xx - xo[zz]; }
    }
    const int rows = sh ? N_TOK : cz[z];
    const int r0 = xl * 256;
    const int c0 = y * 128;

    __shared__ __align__(16) unsigned short lds[3 * 12288];   // 72 KiB, 3-buffer ring

    const int t = threadIdx.x;
    const int lane = t & 63;
    const int wv = t >> 6;
    const int wm = wv >> 1;               // 0..3 -> 64-row band
    const int wn = wv & 1;                // 0..1 -> 64-col band

    const int widx = sh ? (PHASE == 0 ? 0 : 1) : (PHASE == 0 ? 2 + z : 10 + z);
    const unsigned short* Bmat = WtAll + (size_t)widx * C_DIM * C_DIM;
    const int* bk = buckets + z * N_TOK;

    // staging geometry: slot index S -> row S>>2, 16B slot S&3 (==lane&3).
    // A instr j (j=0,1): rows j*128 + wv*16 + (lane>>2); B instr: rows wv*16 + (lane>>2)
    // global source col pre-swizzled: (lane&3) ^ ((lane>>3)&3)
    const int scol = (((lane & 3) ^ ((lane >> 3) & 3)) * 8);
    const int rA0 = wv * 16 + (lane >> 2);
    const int rA1 = 128 + rA0;
    int g0, g1;
    const unsigned short* Asrc;
    if (sh) {
        Asrc = Adir;
        g0 = r0 + rA0; g1 = r0 + rA1;
    } else {
        Asrc = Agat;
        int p0 = r0 + rA0, p1 = r0 + rA1;
        int e0v = bk[p0 < rows ? p0 : rows - 1];
        int e1v = bk[p1 < rows ? p1 : rows - 1];
        g0 = (PHASE == 0) ? (e0v >> 1) : e0v;
        g1 = (PHASE == 0) ? (e1v >> 1) : e1v;
    }
    const unsigned short* ap0 = Asrc + (size_t)g0 * C_DIM + scol;
    const unsigned short* ap1 = Asrc + (size_t)g1 * C_DIM + scol;
    const unsigned short* bp  = Bmat + (size_t)(c0 + rA0) * C_DIM + scol;

    f32x4 acc[4][4];
    #pragma unroll
    for (int i = 0; i < 4; i++)
        #pragma unroll
        for (int j = 0; j < 4; j++) acc[i][j] = (f32x4){0.f, 0.f, 0.f, 0.f};

    // fragment-read swizzled k-slot: slot = fq ^ ((fr>>1)&3)
    const int fr = lane & 15;
    const int fq = lane >> 4;
    const int ks = ((fq ^ ((fr >> 1) & 3)) * 8);

    // prologue: stage tiles 0,1 into buffers 0,1 (6 vm-ops per thread outstanding)
    #pragma unroll
    for (int p = 0; p < 2; ++p) {
        unsigned short* d = lds + p * 12288;
        const int ko = p * 32;
        GLOAD_LDS(ap0 + ko, d + wv * 512 + lane * 8);
        GLOAD_LDS(ap1 + ko, d + 4096 + wv * 512 + lane * 8);
        GLOAD_LDS(bp + ko,  d + 8192 + wv * 512 + lane * 8);
    }

    #pragma unroll
    for (int kt = 0; kt < NTK; ++kt) {
        if (kt + 1 < NTK) { WAITVM(3); }   // tile kt landed; tile kt+1 (and kt+2 later) in flight
        else              { WAITVM(0); }
        BAR();          // tile kt visible; all waves done reading buf[(kt+2)%3]'s old tile
        SCHEDB();
        if (kt + 2 < NTK) {
            unsigned short* d = lds + ((kt + 2) % 3) * 12288;
            const int ko = (kt + 2) * 32;
            GLOAD_LDS(ap0 + ko, d + wv * 512 + lane * 8);
            GLOAD_LDS(ap1 + ko, d + 4096 + wv * 512 + lane * 8);
            GLOAD_LDS(bp + ko,  d + 8192 + wv * 512 + lane * 8);
        }
        SCHEDB();       // stage issued before compute; compute may not hoist above
        const unsigned short* buf = lds + (kt % 3) * 12288;
        short8 afr[4], bfr[4];
        #pragma unroll
        for (int i = 0; i < 4; i++)
            afr[i] = *reinterpret_cast<const short8*>(buf + (size_t)(wm * 64 + i * 16 + fr) * 32 + ks);
        #pragma unroll
        for (int j = 0; j < 4; j++)
            bfr[j] = *reinterpret_cast<const short8*>(buf + 8192 + (size_t)(wn * 64 + j * 16 + fr) * 32 + ks);
        __builtin_amdgcn_s_setprio(1);
        #pragma unroll
        for (int i = 0; i < 4; i++)
            #pragma unroll
            for (int j = 0; j < 4; j++)
                acc[i][j] = __builtin_amdgcn_mfma_f32_16x16x32_bf16(
                    __builtin_bit_cast(bf16x8, afr[i]), __builtin_bit_cast(bf16x8, bfr[j]), acc[i][j], 0, 0, 0);
        __builtin_amdgcn_s_setprio(0);
        // single barrier per step: stage(kt+2) targets buf[(kt-1)%3], whose readers all
        // passed this step's BAR before the overwrite begins.
    }

    // ---- epilogue: rows r0 + wm*64 + i*16 + fq*4 + rr; cols c0 + wn*64 + j*16 + fr ----
    const int orow = r0 + wm * 64;
    const int ocol = c0 + wn * 64;
    if (sh) {
        if constexpr (PHASE == 0) {
            unsigned short* Hd = (unsigned short*)dstDir;
            #pragma unroll
            for (int i = 0; i < 4; i++)
                #pragma unroll
                for (int rr = 0; rr < 4; rr++) {
                    size_t base = (size_t)(orow + i * 16 + fq * 4 + rr) * C_DIM;
                    #pragma unroll
                    for (int j = 0; j < 4; j++) {
                        float v = acc[i][j][rr];
                        float rl = v > 0.f ? v : 0.f;
                        Hd[base + ocol + j * 16 + fr] = f2bf(rl * rl);
                    }
                }
        } else {
            float* od = (float*)dstDir;
            #pragma unroll
            for (int i = 0; i < 4; i++)
                #pragma unroll
                for (int rr = 0; rr < 4; rr++) {
                    size_t base = (size_t)(orow + i * 16 + fq * 4 + rr) * C_DIM;
                    #pragma unroll
                    for (int j = 0; j < 4; j++)
                        od[base + ocol + j * 16 + fr] = acc[i][j][rr];
                }
        }
    } else {
        #pragma unroll
        for (int i = 0; i < 4; i++)
            #pragma unroll
            for (int rr = 0; rr < 4; rr++) {
                int pos = orow + i * 16 + fq * 4 + rr;
                if (pos < rows) {
                    int ent = bk[pos];
                    size_t base = (size_t)ent * C_DIM;
                    #pragma unroll
                    for (int j = 0; j < 4; j++) {
                        float v = acc[i][j][rr];
                        if (PHASE == 0) {
                            float rl = v > 0.f ? v : 0.f;
                            dstGat[base + ocol + j * 16 + fr] = f2bf(rl * rl);
                        } else {
                            dstGat[base + ocol + j * 16 + fr] = f2bf(v);
                        }
                    }
                }
            }
    }
}

// ---------------- combine: out += w0*Y[n,0] + w1*Y[n,1] ----------------
__global__ void combine_kernel(float* __restrict__ out, const unsigned short* __restrict__ Y,
                               const float* __restrict__ tw) {
    int idx = blockIdx.x * blockDim.x + threadIdx.x;
    const int per_row = C_DIM / 4;
    if (idx >= N_TOK * per_row) return;
    int n = idx / per_row;
    int c = (idx % per_row) * 4;
    float w0 = tw[n * 2], w1 = tw[n * 2 + 1];
    const ushort4 a = *reinterpret_cast<const ushort4*>(Y + (size_t)(n * 2) * C_DIM + c);
    const ushort4 b = *reinterpret_cast<const ushort4*>(Y + (size_t)(n * 2 + 1) * C_DIM + c);
    float4* op = reinterpret_cast<float4*>(out + (size_t)n * C_DIM + c);
    float4 o = *op;
    o.x += w0 * bf2f(a.x) + w1 * bf2f(b.x);
    o.y += w0 * bf2f(a.y) + w1 * bf2f(b.y);
    o.z += w0 * bf2f(a.z) + w1 * bf2f(b.z);
    o.w += w0 * bf2f(a.w) + w1 * bf2f(b.w);
    *op = o;
}

extern "C" void kernel_launch(void* const* d_in, const int* in_sizes, int n_in,
                              void* d_out, int out_size, void* d_ws, size_t ws_size,
                              hipStream_t stream) {
    const float* x   = (const float*)d_in[0];
    const float* wfc = (const float*)d_in[1];
    const float* wpj = (const float*)d_in[2];
    const float* w1  = (const float*)d_in[3];
    const float* w2  = (const float*)d_in[4];
    const float* rw  = (const float*)d_in[5];
    const float* bias= (const float*)d_in[6];
    float* out = (float*)d_out;

    char* ws = (char*)d_ws;
    size_t off = 0;
    auto alloc = [&](size_t bytes) { void* p = ws + off; off += (bytes + 255) & ~(size_t)255; return p; };
    unsigned short* xb   = (unsigned short*)alloc((size_t)N_TOK * C_DIM * 2);
    unsigned short* Wt   = (unsigned short*)alloc((size_t)18 * C_DIM * C_DIM * 2);
    unsigned short* H    = (unsigned short*)alloc((size_t)N_TOK * 2 * C_DIM * 2);  // expert hidden, by entry
    unsigned short* Hsh  = (unsigned short*)alloc((size_t)N_TOK * C_DIM * 2);      // shared hidden
    unsigned short* Y    = (unsigned short*)alloc((size_t)N_TOK * 2 * C_DIM * 2);  // expert out, by entry
    float* topk_w        = (float*)alloc((size_t)N_TOK * 2 * 4);
    int* counts          = (int*)alloc(256);
    int* buckets         = (int*)alloc((size_t)E_NUM * N_TOK * 4);
    int* eids            = (int*)alloc((size_t)2 * N_TOK * 4);

    prep_kernel<<<PREP_TOT, 256, 0, stream>>>(wfc, wpj, w1, w2, Wt, x, rw, bias, topk_w, eids, xb);
    bucketize_kernel<<<E_NUM, 1024, 0, stream>>>(eids, counts, buckets);

    gemm_all_kernel<0><<<GRIDG, 512, 0, stream>>>(xb, xb, Wt, Hsh, H, counts, buckets);
    gemm_all_kernel<1><<<GRIDG, 512, 0, stream>>>(Hsh, H, Wt, out, Y, counts, buckets);

    combine_kernel<<<(N_TOK * (C_DIM / 4) + 255) / 256, 256, 0, stream>>>(out, Y, topk_w);
}